// Round 17
// baseline (123.667 us; speedup 1.0000x reference)
//
#include <hip/hip_runtime.h>

// Sinkhorn image loss — conv form (R=10), TRIPLE fusion + dy-fold, 8 dispatches.
//   K = exp(-C/eps) = exp(-1.5045*d_pix): radial 21x21 stencil (R=10 tail
//   ~3e-6 rel; absmax 0.0 verified rounds 13-16). Weights from C row 1176.
//   Chain: a1 | [b1,a2,b2] [a3,b3,a4] [b4,a5,b5] [a6,b6,a7] [b7,a8,b8]
//          [a9,b9,a10] | cost(+b10).  8 dispatches total.
//   dy-fold: w(dy)=w(-dy) bitwise -> acc += w[d]*(row[y-d]+row[y+d]):
//   441 FMA/output -> 231 FMA + 10 ADD (0.55x VALU).
//
// sk_triple: 256 blocks (16 b x 16 slices of 3 rows), 512 thr. Tile chain in
// LDS: vl0 63 rows (apron) -> t1 43 rows -> t2 23 rows -> 3 output rows.
// Per conv: fine-grained tasks (516/506/132 at ~550-VALU grain — round-16
// lesson: grain sets phase time), partials at stride-28/20 slots (8 start
// banks). Full-width tiles: x never tiled (image is 48 wide + zero halo).

namespace {

constexpr int N    = 2304;   // 48*48
constexpr int B    = 16;
constexpr int NB   = N * B;
constexpr int R    = 10;
constexpr int WIN  = 21;
constexpr int WPAD = 24;
constexpr int APX  = 12;     // aligned x-apron; taps at word offset +2
constexpr int AST  = 76;     // LDS row stride (words)
constexpr int NOUT = 144;
constexpr int NTH  = WIN * 12;  // 252 (a1/cost kernels)
constexpr int AVR1 = 23;
// triple-kernel tile rows
constexpr int V0R  = 63;     // input apron rows (3 + 6R)
constexpr int T1R  = 43;     // conv1 output rows
constexpr int T2R  = 23;     // conv2 output rows
// partials: conv1 6 lvls x 86 slots x 28; conv2 11 x 46 x 28; conv3 11x12x20
constexpr int P1S  = 2408;   // 86*28 words per conv1 level
constexpr int P2S  = 1288;   // 46*28
constexpr int P3S  = 240;    // 12*20

__device__ __forceinline__ float wave_sum(float v) {
#pragma unroll
    for (int off = 32; off >= 1; off >>= 1) v += __shfl_xor(v, off);
    return v;
}

template <bool WC, int NT>
__device__ __forceinline__ void stage_wt(float* wtl, float* wcl,
                                         const float* __restrict__ C) {
    for (int i = threadIdx.x; i < WIN * WPAD; i += NT) {
        const int dy = i / WPAD, dx = i - dy * WPAD;
        float wv = 0.f, wc = 0.f;
        if (dx < WIN) {
            const float c = C[1176 * N + (14 + dy) * 48 + (14 + dx)];
            wv = __expf(c * -100.f);
            wc = wv * c;
        }
        wtl[i] = wv;
        if (WC) wcl[i] = wc;
    }
}

template <bool ONES, int NT>
__device__ __forceinline__ void stage_ap(float* vl, const float* img,
                                         int b, int ytop, int nrows) {
    for (int i = threadIdx.x; i < nrows * 18; i += NT) {
        const int rr = i / 18, c4 = i - rr * 18;
        const int y = ytop + rr, x0 = c4 * 4 - APX;
        float4 v = make_float4(0.f, 0.f, 0.f, 0.f);
        if ((unsigned)y < 48u && (unsigned)x0 < 48u)
            v = ONES ? make_float4(1.f, 1.f, 1.f, 1.f)
                     : *(const float4*)(img + b * N + y * 48 + x0);
        *(float4*)&vl[rr * AST + c4 * 4] = v;
    }
}

// ---- conv primitives: acc[k] += w[dx]*row[k+2+dx] --------------------------
__device__ __forceinline__ void conv_c12(const float* vp, const float* wp,
                                         float* acc) {
    float vr[36], wr[24];
#pragma unroll
    for (int c = 0; c < 9; ++c) *(float4*)&vr[4 * c] = *(const float4*)&vp[4 * c];
#pragma unroll
    for (int c = 0; c < 6; ++c) *(float4*)&wr[4 * c] = *(const float4*)&wp[4 * c];
#pragma unroll
    for (int dx = 0; dx < WIN; ++dx)
#pragma unroll
        for (int k = 0; k < 12; ++k)
            acc[k] = fmaf(wr[dx], vr[k + 2 + dx], acc[k]);
}
__device__ __forceinline__ void conv_p12(const float* lo, const float* hi,
                                         const float* wp, float* acc) {
    float vr[36], wr[24];
#pragma unroll
    for (int c = 0; c < 9; ++c) {
        const float4 a = *(const float4*)&lo[4 * c];
        const float4 b = *(const float4*)&hi[4 * c];
        vr[4 * c]     = a.x + b.x;
        vr[4 * c + 1] = a.y + b.y;
        vr[4 * c + 2] = a.z + b.z;
        vr[4 * c + 3] = a.w + b.w;
    }
#pragma unroll
    for (int c = 0; c < 6; ++c) *(float4*)&wr[4 * c] = *(const float4*)&wp[4 * c];
#pragma unroll
    for (int dx = 0; dx < WIN; ++dx)
#pragma unroll
        for (int k = 0; k < 12; ++k)
            acc[k] = fmaf(wr[dx], vr[k + 2 + dx], acc[k]);
}
__device__ __forceinline__ void conv_c24(const float* vp, const float* wp,
                                         float* acc) {
    float vr[48], wr[24];
#pragma unroll
    for (int c = 0; c < 12; ++c) *(float4*)&vr[4 * c] = *(const float4*)&vp[4 * c];
#pragma unroll
    for (int c = 0; c < 6; ++c) *(float4*)&wr[4 * c] = *(const float4*)&wp[4 * c];
#pragma unroll
    for (int dx = 0; dx < WIN; ++dx)
#pragma unroll
        for (int k = 0; k < 24; ++k)
            acc[k] = fmaf(wr[dx], vr[k + 2 + dx], acc[k]);
}
__device__ __forceinline__ void conv_p24(const float* lo, const float* hi,
                                         const float* wp, float* acc) {
    float vr[48], wr[24];
#pragma unroll
    for (int c = 0; c < 12; ++c) {
        const float4 a = *(const float4*)&lo[4 * c];
        const float4 b = *(const float4*)&hi[4 * c];
        vr[4 * c]     = a.x + b.x;
        vr[4 * c + 1] = a.y + b.y;
        vr[4 * c + 2] = a.z + b.z;
        vr[4 * c + 3] = a.w + b.w;
    }
#pragma unroll
    for (int c = 0; c < 6; ++c) *(float4*)&wr[4 * c] = *(const float4*)&wp[4 * c];
#pragma unroll
    for (int dx = 0; dx < WIN; ++dx)
#pragma unroll
        for (int k = 0; k < 24; ++k)
            acc[k] = fmaf(wr[dx], vr[k + 2 + dx], acc[k]);
}

// ------------------------------------------------------------- a1 ---------
// (verbatim round-13/16-proven) rowsum = K*1; A0 = softmax/rowsum; smstat.
__global__ __launch_bounds__(256) void sk_a1(const float* __restrict__ logits,
                                             const float* __restrict__ C,
                                             float* __restrict__ smstat,
                                             float* __restrict__ A0,
                                             float* __restrict__ out) {
    __shared__ float vl[AVR1 * AST];
    __shared__ float wtl[WIN * WPAD];
    __shared__ float part[NTH * 12];
    __shared__ float sred[8];

    const int bid = blockIdx.x;
    const int b   = bid & 15;
    const int y0  = (bid >> 4) * 3;
    const int tid = threadIdx.x, w = tid >> 6, lane = tid & 63;

    stage_wt<false, 256>(wtl, nullptr, C);
    stage_ap<true, 256>(vl, nullptr, b, y0 - R, AVR1);

    float xs[9];
    float m = -3.0e38f;
#pragma unroll
    for (int s9 = 0; s9 < 9; ++s9) {
        xs[s9] = logits[b * N + s9 * 256 + tid];
        m = fmaxf(m, xs[s9]);
    }
#pragma unroll
    for (int off = 32; off >= 1; off >>= 1) m = fmaxf(m, __shfl_xor(m, off));
    if (lane == 0) sred[w] = m;
    __syncthreads();
    m = fmaxf(fmaxf(sred[0], sred[1]), fmaxf(sred[2], sred[3]));
    float sum = 0.f;
#pragma unroll
    for (int s9 = 0; s9 < 9; ++s9) sum += __expf(xs[s9] - m);
#pragma unroll
    for (int off = 32; off >= 1; off >>= 1) sum += __shfl_xor(sum, off);
    __syncthreads();
    if (lane == 0) sred[4 + w] = sum;
    __syncthreads();
    sum = sred[4] + sred[5] + sred[6] + sred[7];
    const float sm_m = m, sm_inv = 1.f / sum;
    if (tid == 0 && (bid >> 4) == 0) {
        smstat[2 * b]     = sm_m;
        smstat[2 * b + 1] = sm_inv;
        if (b == 0) out[0] = 0.f;
    }
    __syncthreads();

    if (tid < NTH) {
        const int dy = tid / 12, strip = tid - dy * 12;
        const int r = strip >> 2, xw = (strip & 3) * 12;
        float acc[12];
#pragma unroll
        for (int k = 0; k < 12; ++k) acc[k] = 0.f;
        conv_c12(&vl[(r + dy) * AST + xw], &wtl[dy * WPAD], acc);
#pragma unroll
        for (int c = 0; c < 3; ++c)
            *(float4*)&part[tid * 12 + 4 * c] = *(float4*)&acc[4 * c];
    }
    __syncthreads();

    if (tid < NOUT) {
        float ssum = 0.f;
#pragma unroll
        for (int d = 0; d < WIN; ++d) ssum += part[d * 144 + tid];
        const int o = b * N + (y0 + tid / 48) * 48 + (tid % 48);
        A0[o] = __expf(logits[o] - sm_m) * sm_inv / ssum;
    }
}

// ------------------------------------------------------------- triple -----
// PAR=0: stages produce (b,a,b) i.e. divides by (q,p,q); PAR=1: (p,q,p).
template <int PAR>
__global__ __launch_bounds__(512) void sk_triple(const float* __restrict__ logits,
                                                 const float* __restrict__ target,
                                                 const float* __restrict__ C,
                                                 const float* __restrict__ smstat,
                                                 const float* __restrict__ Ain,
                                                 float* __restrict__ Aout) {
    __shared__ float vl0[V0R * AST];   // 19152 B
    __shared__ float t1[T1R * AST];    // 13072 B
    __shared__ float t2[T2R * AST];    //  6992 B
    __shared__ float wtl[WIN * WPAD];  //  2016 B
    __shared__ float part[6 * P1S];    // 57792 B   (reused by conv2/conv3)

    const int bid = blockIdx.x;
    const int b   = bid & 15;
    const int y0  = (bid >> 4) * 3;
    const int tid = threadIdx.x;

    stage_ap<false, 512>(vl0, Ain, b, y0 - 30, V0R);   // long-latency first
    stage_wt<false, 512>(wtl, nullptr, C);
    for (int i = tid; i < T1R * AST; i += 512) t1[i] = 0.f;
    for (int i = tid; i < T2R * AST; i += 512) t2[i] = 0.f;
    const float sm_m = smstat[2 * b], sm_inv = smstat[2 * b + 1];
    __syncthreads();

    // ---- conv1: 516 tasks (uc<6, rb<43, xg<2); fold levels per uc ---------
    for (int tau = tid; tau < 516; tau += 512) {
        const int uc = tau / 86, slot = tau - uc * 86;
        const int rb = slot >> 1, xw = (slot & 1) * 24;
        float acc[24];
#pragma unroll
        for (int k = 0; k < 24; ++k) acc[k] = 0.f;
        if (uc == 0) {
            conv_c24(&vl0[(rb + 10) * AST + xw], &wtl[10 * WPAD], acc);
            conv_p24(&vl0[(rb + 9) * AST + xw], &vl0[(rb + 11) * AST + xw],
                     &wtl[11 * WPAD], acc);
        } else if (uc < 5) {
            const int d = 2 * uc;
            conv_p24(&vl0[(rb + 10 - d) * AST + xw],
                     &vl0[(rb + 10 + d) * AST + xw], &wtl[(10 + d) * WPAD], acc);
            conv_p24(&vl0[(rb + 9 - d) * AST + xw],
                     &vl0[(rb + 11 + d) * AST + xw], &wtl[(11 + d) * WPAD], acc);
        } else {
            conv_p24(&vl0[rb * AST + xw], &vl0[(rb + 20) * AST + xw],
                     &wtl[20 * WPAD], acc);
        }
        float* pp = &part[uc * P1S + slot * 28];
#pragma unroll
        for (int c = 0; c < 6; ++c) *(float4*)&pp[4 * c] = *(float4*)&acc[4 * c];
    }
    __syncthreads();

    // ---- reduce1 -> t1 (divide by src1) -----------------------------------
    for (int o = tid; o < T1R * 48; o += 512) {
        const int rt = o / 48, x = o - rt * 48;
        const int slot = rt * 2 + (x >= 24 ? 1 : 0);
        const int k = x >= 24 ? x - 24 : x;
        float s = 0.f;
#pragma unroll
        for (int l = 0; l < 6; ++l) s += part[l * P1S + slot * 28 + k];
        const int y = y0 - 20 + rt;
        if ((unsigned)y < 48u) {
            const int g = b * N + y * 48 + x;
            const float sv = (PAR == 0) ? (target[g] + 1e-8f)
                                        : __expf(logits[g] - sm_m) * sm_inv;
            t1[rt * AST + APX + x] = sv / s;
        }
    }
    __syncthreads();

    // ---- conv2: 506 tasks (u<11, rt2<23, xg<2) ----------------------------
    if (tid < 506) {
        const int u = tid / 46, slot = tid - u * 46;
        const int rt2 = slot >> 1, xw = (slot & 1) * 24;
        float acc[24];
#pragma unroll
        for (int k = 0; k < 24; ++k) acc[k] = 0.f;
        if (u == 0) conv_c24(&t1[(rt2 + 10) * AST + xw], &wtl[10 * WPAD], acc);
        else        conv_p24(&t1[(rt2 + 10 - u) * AST + xw],
                             &t1[(rt2 + 10 + u) * AST + xw],
                             &wtl[(10 + u) * WPAD], acc);
        float* pp = &part[u * P2S + slot * 28];
#pragma unroll
        for (int c = 0; c < 6; ++c) *(float4*)&pp[4 * c] = *(float4*)&acc[4 * c];
    }
    __syncthreads();

    // ---- reduce2 -> t2 (divide by src2) -----------------------------------
    for (int o = tid; o < T2R * 48; o += 512) {
        const int rt = o / 48, x = o - rt * 48;
        const int slot = rt * 2 + (x >= 24 ? 1 : 0);
        const int k = x >= 24 ? x - 24 : x;
        float s = 0.f;
#pragma unroll
        for (int l = 0; l < 11; ++l) s += part[l * P2S + slot * 28 + k];
        const int y = y0 - 10 + rt;
        if ((unsigned)y < 48u) {
            const int g = b * N + y * 48 + x;
            const float sv = (PAR == 0) ? __expf(logits[g] - sm_m) * sm_inv
                                        : (target[g] + 1e-8f);
            t2[rt * AST + APX + x] = sv / s;
        }
    }
    __syncthreads();

    // ---- conv3: 132 tasks (u<11, ra<3, xq<4), 12-wide ---------------------
    if (tid < 132) {
        const int u = tid / 12, slot = tid - u * 12;
        const int ra = slot >> 2, xw = (slot & 3) * 12;
        float acc[12];
#pragma unroll
        for (int k = 0; k < 12; ++k) acc[k] = 0.f;
        if (u == 0) conv_c12(&t2[(ra + 10) * AST + xw], &wtl[10 * WPAD], acc);
        else        conv_p12(&t2[(ra + 10 - u) * AST + xw],
                             &t2[(ra + 10 + u) * AST + xw],
                             &wtl[(10 + u) * WPAD], acc);
        float* pp = &part[u * P3S + slot * 20];
#pragma unroll
        for (int c = 0; c < 3; ++c) *(float4*)&pp[4 * c] = *(float4*)&acc[4 * c];
    }
    __syncthreads();

    // ---- reduce3 -> global (divide by src3) -------------------------------
    if (tid < NOUT) {
        const int ra = tid / 48, x = tid - ra * 48;
        const int slot = ra * 4 + x / 12, k = x % 12;
        float s = 0.f;
#pragma unroll
        for (int l = 0; l < 11; ++l) s += part[l * P3S + slot * 20 + k];
        const int g = b * N + (y0 + ra) * 48 + x;
        const float sv = (PAR == 0) ? (target[g] + 1e-8f)
                                    : __expf(logits[g] - sm_m) * sm_inv;
        Aout[g] = sv / s;
    }
}

// ------------------------------------------------------------- cost -------
// (verbatim round-13/16-proven) s1 = K a10, s2 = (K.C) a10; q/s1*s2; atomic.
__global__ __launch_bounds__(256) void sk_cost(const float* __restrict__ target,
                                               const float* __restrict__ C,
                                               const float* __restrict__ Ain,
                                               float* __restrict__ out) {
    __shared__ float vl[AVR1 * AST];
    __shared__ float wtl[WIN * WPAD], wcl[WIN * WPAD];
    __shared__ float p1[NTH * 12], p2[NTH * 12];
    __shared__ float sred[4];

    const int bid = blockIdx.x;
    const int b   = bid & 15;
    const int y0  = (bid >> 4) * 3;
    const int tid = threadIdx.x, w = tid >> 6, lane = tid & 63;

    stage_wt<true, 256>(wtl, wcl, C);
    stage_ap<false, 256>(vl, Ain, b, y0 - R, AVR1);
    __syncthreads();

    if (tid < NTH) {
        const int dy = tid / 12, strip = tid - dy * 12;
        const int r = strip >> 2, xw = (strip & 3) * 12;
        float a1[12], a2[12];
#pragma unroll
        for (int k = 0; k < 12; ++k) { a1[k] = 0.f; a2[k] = 0.f; }
        float vr[36], wr[24], cr[24];
        const float* vp = &vl[(r + dy) * AST + xw];
#pragma unroll
        for (int c = 0; c < 9; ++c)
            *(float4*)&vr[4 * c] = *(const float4*)&vp[4 * c];
#pragma unroll
        for (int c = 0; c < 6; ++c) {
            *(float4*)&wr[4 * c] = *(const float4*)&wtl[dy * WPAD + 4 * c];
            *(float4*)&cr[4 * c] = *(const float4*)&wcl[dy * WPAD + 4 * c];
        }
#pragma unroll
        for (int dx = 0; dx < WIN; ++dx)
#pragma unroll
            for (int k = 0; k < 12; ++k) {
                a1[k] = fmaf(wr[dx], vr[k + 2 + dx], a1[k]);
                a2[k] = fmaf(cr[dx], vr[k + 2 + dx], a2[k]);
            }
#pragma unroll
        for (int c = 0; c < 3; ++c) {
            *(float4*)&p1[tid * 12 + 4 * c] = *(float4*)&a1[4 * c];
            *(float4*)&p2[tid * 12 + 4 * c] = *(float4*)&a2[4 * c];
        }
    }
    __syncthreads();

    float val = 0.f;
    if (tid < NOUT) {
        float s1 = 0.f, s2 = 0.f;
#pragma unroll
        for (int d = 0; d < WIN; ++d) {
            s1 += p1[d * 144 + tid];
            s2 += p2[d * 144 + tid];
        }
        const int o = b * N + (y0 + tid / 48) * 48 + (tid % 48);
        val = (target[o] + 1e-8f) / s1 * s2;
    }
    val = wave_sum(val);
    if (lane == 0) sred[w] = val;
    __syncthreads();
    if (tid == 0)
        atomicAdd(out, (sred[0] + sred[1] + sred[2] + sred[3]) * (1.f / 16.f));
}

}  // namespace

extern "C" void kernel_launch(void* const* d_in, const int* in_sizes, int n_in,
                              void* d_out, int out_size, void* d_ws, size_t ws_size,
                              hipStream_t stream) {
    const float* logits = (const float*)d_in[0];   // (B, 48, 48)
    const float* target = (const float*)d_in[1];   // (B, 48, 48)
    const float* C      = (const float*)d_in[2];   // (1, N, N)
    float* out = (float*)d_out;
    float* ws  = (float*)d_ws;

    float* smstat = ws;            // [32]
    float* A0     = ws + 32;       // [B][N]
    float* A1     = A0 + NB;       // [B][N]

    sk_a1<<<256, 256, 0, stream>>>(logits, C, smstat, A0, out);

    // 6 triples: a1 ->b2-> a4 ->b5-> a7 ->b8-> a10 (alternating parity)
    float* bufs[2] = {A0, A1};
    for (int t = 0; t < 6; ++t) {
        if ((t & 1) == 0)
            sk_triple<0><<<256, 512, 0, stream>>>(logits, target, C, smstat,
                                                  bufs[t & 1], bufs[(t + 1) & 1]);
        else
            sk_triple<1><<<256, 512, 0, stream>>>(logits, target, C, smstat,
                                                  bufs[t & 1], bufs[(t + 1) & 1]);
    }

    sk_cost<<<256, 256, 0, stream>>>(target, C, A0, out);
}

// Round 18
// 95.686 us; speedup vs baseline: 1.2924x; 1.2924x over previous
//
#include <hip/hip_runtime.h>

// Sinkhorn image loss — conv form (R=10), 11 dispatches, dy-folded pair fusion.
//   K = exp(-C/eps) = exp(-1.5045*d_pix): radial 21x21 stencil (R=10 tail
//   ~3e-6 rel; absmax 0.0 verified rounds 13-17). Weights from C row 1176.
//   a1 = p/(K*1); 9 x fused {b_t = q/(K a_t); a_{t+1} = p/(K b_t)}; b10+cost.
//
// Round-17 post-mortem: triple fusion (97KB LDS, 43-row mid-tile) broke block
// concurrency (0.2% occupancy) + 1.8x redundant work -> reverted. But its
// dy-fold (w(dy)=w(-dy) bitwise, conv_p24) passed absmax 0.0 -> reuse HERE,
// in the round-16-champion pair structure:
//   conv1: 506 fold-tasks (u<11, rb<23, xg<2), 504 FMA grain -> 0.95us
//   conv2: 132 fold-tasks (u<11, ra<3, 12-wide)  -> ~0.25us (was 1-wave 0.84)
//   target/logits prefetched to regs before conv1 (hides dispatch-inv latency)
//   LDS 74.7 KB (stride-26 partial slots) — round-16-proven regime.

namespace {

constexpr int N    = 2304;   // 48*48
constexpr int B    = 16;
constexpr int NB   = N * B;
constexpr int R    = 10;
constexpr int WIN  = 21;
constexpr int WPAD = 24;
constexpr int APX  = 12;     // aligned x-apron; taps at word offset +2
constexpr int AST  = 76;     // LDS row stride (words)
constexpr int NOUT = 144;
constexpr int NTH  = WIN * 12;  // 252 (a1/cost kernels)
constexpr int AVR1 = 23;     // apron rows, single conv (3+2R)
constexpr int AVR2 = 43;     // apron rows, fused (3+4R)
constexpr int BVR  = 23;     // b-tile rows
constexpr int P1L  = 46 * 26;   // 1196 words per conv1 fold level
constexpr int P2L  = 12 * 14;   // 168 words per conv2 fold level

__device__ __forceinline__ float wave_sum(float v) {
#pragma unroll
    for (int off = 32; off >= 1; off >>= 1) v += __shfl_xor(v, off);
    return v;
}

template <bool WC, int NT>
__device__ __forceinline__ void stage_wt(float* wtl, float* wcl,
                                         const float* __restrict__ C) {
    for (int i = threadIdx.x; i < WIN * WPAD; i += NT) {
        const int dy = i / WPAD, dx = i - dy * WPAD;
        float wv = 0.f, wc = 0.f;
        if (dx < WIN) {
            const float c = C[1176 * N + (14 + dy) * 48 + (14 + dx)];
            wv = __expf(c * -100.f);
            wc = wv * c;
        }
        wtl[i] = wv;
        if (WC) wcl[i] = wc;
    }
}

template <bool ONES, int NT>
__device__ __forceinline__ void stage_ap(float* vl, const float* img,
                                         int b, int ytop, int nrows) {
    for (int i = threadIdx.x; i < nrows * 18; i += NT) {
        const int rr = i / 18, c4 = i - rr * 18;
        const int y = ytop + rr, x0 = c4 * 4 - APX;
        float4 v = make_float4(0.f, 0.f, 0.f, 0.f);
        if ((unsigned)y < 48u && (unsigned)x0 < 48u)
            v = ONES ? make_float4(1.f, 1.f, 1.f, 1.f)
                     : *(const float4*)(img + b * N + y * 48 + x0);
        *(float4*)&vl[rr * AST + c4 * 4] = v;
    }
}

// ---- conv primitives (round-17-verified): acc[k] += w[dx]*row[k+2+dx] -----
__device__ __forceinline__ void conv_c12(const float* vp, const float* wp,
                                         float* acc) {
    float vr[36], wr[24];
#pragma unroll
    for (int c = 0; c < 9; ++c) *(float4*)&vr[4 * c] = *(const float4*)&vp[4 * c];
#pragma unroll
    for (int c = 0; c < 6; ++c) *(float4*)&wr[4 * c] = *(const float4*)&wp[4 * c];
#pragma unroll
    for (int dx = 0; dx < WIN; ++dx)
#pragma unroll
        for (int k = 0; k < 12; ++k)
            acc[k] = fmaf(wr[dx], vr[k + 2 + dx], acc[k]);
}
__device__ __forceinline__ void conv_p12(const float* lo, const float* hi,
                                         const float* wp, float* acc) {
    float vr[36], wr[24];
#pragma unroll
    for (int c = 0; c < 9; ++c) {
        const float4 a = *(const float4*)&lo[4 * c];
        const float4 b = *(const float4*)&hi[4 * c];
        vr[4 * c]     = a.x + b.x;
        vr[4 * c + 1] = a.y + b.y;
        vr[4 * c + 2] = a.z + b.z;
        vr[4 * c + 3] = a.w + b.w;
    }
#pragma unroll
    for (int c = 0; c < 6; ++c) *(float4*)&wr[4 * c] = *(const float4*)&wp[4 * c];
#pragma unroll
    for (int dx = 0; dx < WIN; ++dx)
#pragma unroll
        for (int k = 0; k < 12; ++k)
            acc[k] = fmaf(wr[dx], vr[k + 2 + dx], acc[k]);
}
__device__ __forceinline__ void conv_c24(const float* vp, const float* wp,
                                         float* acc) {
    float vr[48], wr[24];
#pragma unroll
    for (int c = 0; c < 12; ++c) *(float4*)&vr[4 * c] = *(const float4*)&vp[4 * c];
#pragma unroll
    for (int c = 0; c < 6; ++c) *(float4*)&wr[4 * c] = *(const float4*)&wp[4 * c];
#pragma unroll
    for (int dx = 0; dx < WIN; ++dx)
#pragma unroll
        for (int k = 0; k < 24; ++k)
            acc[k] = fmaf(wr[dx], vr[k + 2 + dx], acc[k]);
}
__device__ __forceinline__ void conv_p24(const float* lo, const float* hi,
                                         const float* wp, float* acc) {
    float vr[48], wr[24];
#pragma unroll
    for (int c = 0; c < 12; ++c) {
        const float4 a = *(const float4*)&lo[4 * c];
        const float4 b = *(const float4*)&hi[4 * c];
        vr[4 * c]     = a.x + b.x;
        vr[4 * c + 1] = a.y + b.y;
        vr[4 * c + 2] = a.z + b.z;
        vr[4 * c + 3] = a.w + b.w;
    }
#pragma unroll
    for (int c = 0; c < 6; ++c) *(float4*)&wr[4 * c] = *(const float4*)&wp[4 * c];
#pragma unroll
    for (int dx = 0; dx < WIN; ++dx)
#pragma unroll
        for (int k = 0; k < 24; ++k)
            acc[k] = fmaf(wr[dx], vr[k + 2 + dx], acc[k]);
}

// ------------------------------------------------------------- a1 ---------
// (verbatim round-13/16-proven) rowsum = K*1; A0 = softmax/rowsum; smstat.
__global__ __launch_bounds__(256) void sk_a1(const float* __restrict__ logits,
                                             const float* __restrict__ C,
                                             float* __restrict__ smstat,
                                             float* __restrict__ A0,
                                             float* __restrict__ out) {
    __shared__ float vl[AVR1 * AST];
    __shared__ float wtl[WIN * WPAD];
    __shared__ float part[NTH * 12];
    __shared__ float sred[8];

    const int bid = blockIdx.x;
    const int b   = bid & 15;
    const int y0  = (bid >> 4) * 3;
    const int tid = threadIdx.x, w = tid >> 6, lane = tid & 63;

    stage_wt<false, 256>(wtl, nullptr, C);
    stage_ap<true, 256>(vl, nullptr, b, y0 - R, AVR1);

    float xs[9];
    float m = -3.0e38f;
#pragma unroll
    for (int s9 = 0; s9 < 9; ++s9) {
        xs[s9] = logits[b * N + s9 * 256 + tid];
        m = fmaxf(m, xs[s9]);
    }
#pragma unroll
    for (int off = 32; off >= 1; off >>= 1) m = fmaxf(m, __shfl_xor(m, off));
    if (lane == 0) sred[w] = m;
    __syncthreads();
    m = fmaxf(fmaxf(sred[0], sred[1]), fmaxf(sred[2], sred[3]));
    float sum = 0.f;
#pragma unroll
    for (int s9 = 0; s9 < 9; ++s9) sum += __expf(xs[s9] - m);
#pragma unroll
    for (int off = 32; off >= 1; off >>= 1) sum += __shfl_xor(sum, off);
    __syncthreads();
    if (lane == 0) sred[4 + w] = sum;
    __syncthreads();
    sum = sred[4] + sred[5] + sred[6] + sred[7];
    const float sm_m = m, sm_inv = 1.f / sum;
    if (tid == 0 && (bid >> 4) == 0) {
        smstat[2 * b]     = sm_m;
        smstat[2 * b + 1] = sm_inv;
        if (b == 0) out[0] = 0.f;
    }
    __syncthreads();

    if (tid < NTH) {
        const int dy = tid / 12, strip = tid - dy * 12;
        const int r = strip >> 2, xw = (strip & 3) * 12;
        float acc[12];
#pragma unroll
        for (int k = 0; k < 12; ++k) acc[k] = 0.f;
        conv_c12(&vl[(r + dy) * AST + xw], &wtl[dy * WPAD], acc);
#pragma unroll
        for (int c = 0; c < 3; ++c)
            *(float4*)&part[tid * 12 + 4 * c] = *(float4*)&acc[4 * c];
    }
    __syncthreads();

    if (tid < NOUT) {
        float ssum = 0.f;
#pragma unroll
        for (int d = 0; d < WIN; ++d) ssum += part[d * 144 + tid];
        const int o = b * N + (y0 + tid / 48) * 48 + (tid % 48);
        A0[o] = __expf(logits[o] - sm_m) * sm_inv / ssum;
    }
}

// ------------------------------------------------------------- fused ------
// Pair [b_t, a_{t+1}] with dy-folded convs; Ain -> Aout (ping-pong).
__global__ __launch_bounds__(512) void sk_fused(const float* __restrict__ logits,
                                                const float* __restrict__ target,
                                                const float* __restrict__ C,
                                                const float* __restrict__ smstat,
                                                const float* __restrict__ Ain,
                                                float* __restrict__ Aout) {
    __shared__ float vl[AVR2 * AST];    // 13072 B
    __shared__ float bt[BVR * AST];     //  6992 B
    __shared__ float part[11 * P1L];    // 52624 B  (reused by conv2)
    __shared__ float wtl[WIN * WPAD];   //  2016 B  -> total 74704 B

    const int bid = blockIdx.x;
    const int b   = bid & 15;
    const int y0  = (bid >> 4) * 3;
    const int tid = threadIdx.x;

    stage_ap<false, 512>(vl, Ain, b, y0 - 2 * R, AVR2);   // long-latency first

    // prefetch globals used after conv1/conv2 (hide dispatch-boundary lat)
    float tpre[3];
#pragma unroll
    for (int j = 0; j < 3; ++j) {
        const int o = tid + j * 512;
        tpre[j] = 0.f;
        if (o < BVR * 48) {
            const int rb = o / 48, x = o - rb * 48;
            const int y = y0 - R + rb;
            if ((unsigned)y < 48u) tpre[j] = target[b * N + y * 48 + x] + 1e-8f;
        }
    }
    float lpre = 0.f;
    if (tid < NOUT)
        lpre = logits[b * N + (y0 + tid / 48) * 48 + (tid % 48)];

    stage_wt<false, 512>(wtl, nullptr, C);
    for (int i = tid; i < BVR * AST; i += 512) bt[i] = 0.f;
    const float sm_m = smstat[2 * b], sm_inv = smstat[2 * b + 1];
    __syncthreads();

    // ---- conv1 (folded): 506 tasks (u<11, rb<23, xg<2) --------------------
    if (tid < 506) {
        const int u = tid / 46, slot = tid - u * 46;
        const int rb = slot >> 1, xw = (slot & 1) * 24;
        float acc[24];
#pragma unroll
        for (int k = 0; k < 24; ++k) acc[k] = 0.f;
        if (u == 0) conv_c24(&vl[(rb + 10) * AST + xw], &wtl[10 * WPAD], acc);
        else        conv_p24(&vl[(rb + 10 - u) * AST + xw],
                             &vl[(rb + 10 + u) * AST + xw],
                             &wtl[(10 + u) * WPAD], acc);
        float* pp = &part[u * P1L + slot * 26];
#pragma unroll
        for (int c = 0; c < 6; ++c) *(float4*)&pp[4 * c] = *(float4*)&acc[4 * c];
    }
    __syncthreads();

    // ---- reduce1 -> b-tile (divide by prefetched q) -----------------------
#pragma unroll
    for (int j = 0; j < 3; ++j) {
        const int o = tid + j * 512;
        if (o < BVR * 48) {
            const int rb = o / 48, x = o - rb * 48;
            const int slot = rb * 2 + (x >= 24 ? 1 : 0);
            const int k = x >= 24 ? x - 24 : x;
            float s = 0.f;
#pragma unroll
            for (int l = 0; l < 11; ++l) s += part[l * P1L + slot * 26 + k];
            const int y = y0 - R + rb;
            if ((unsigned)y < 48u) bt[rb * AST + APX + x] = tpre[j] / s;
        }
    }
    __syncthreads();

    // ---- conv2 (folded): 132 tasks (u<11, ra<3, xq<4), 12-wide ------------
    if (tid < 132) {
        const int u = tid / 12, slot = tid - u * 12;
        const int ra = slot >> 2, xw = (slot & 3) * 12;
        float acc[12];
#pragma unroll
        for (int k = 0; k < 12; ++k) acc[k] = 0.f;
        if (u == 0) conv_c12(&bt[(ra + 10) * AST + xw], &wtl[10 * WPAD], acc);
        else        conv_p12(&bt[(ra + 10 - u) * AST + xw],
                             &bt[(ra + 10 + u) * AST + xw],
                             &wtl[(10 + u) * WPAD], acc);
        float* pp = &part[u * P2L + slot * 14];
#pragma unroll
        for (int c = 0; c < 3; ++c) *(float4*)&pp[4 * c] = *(float4*)&acc[4 * c];
    }
    __syncthreads();

    // ---- reduce2 -> global (divide by prefetched p) -----------------------
    if (tid < NOUT) {
        const int ra = tid / 48, x = tid - ra * 48;
        const int slot = ra * 4 + x / 12, k = x % 12;
        float s = 0.f;
#pragma unroll
        for (int l = 0; l < 11; ++l) s += part[l * P2L + slot * 14 + k];
        const int g = b * N + (y0 + ra) * 48 + x;
        Aout[g] = __expf(lpre - sm_m) * sm_inv / s;
    }
}

// ------------------------------------------------------------- cost -------
// (verbatim round-13/16-proven) s1 = K a10, s2 = (K.C) a10; q/s1*s2; atomic.
__global__ __launch_bounds__(256) void sk_cost(const float* __restrict__ target,
                                               const float* __restrict__ C,
                                               const float* __restrict__ Ain,
                                               float* __restrict__ out) {
    __shared__ float vl[AVR1 * AST];
    __shared__ float wtl[WIN * WPAD], wcl[WIN * WPAD];
    __shared__ float p1[NTH * 12], p2[NTH * 12];
    __shared__ float sred[4];

    const int bid = blockIdx.x;
    const int b   = bid & 15;
    const int y0  = (bid >> 4) * 3;
    const int tid = threadIdx.x, w = tid >> 6, lane = tid & 63;

    stage_wt<true, 256>(wtl, wcl, C);
    stage_ap<false, 256>(vl, Ain, b, y0 - R, AVR1);
    __syncthreads();

    if (tid < NTH) {
        const int dy = tid / 12, strip = tid - dy * 12;
        const int r = strip >> 2, xw = (strip & 3) * 12;
        float a1[12], a2[12];
#pragma unroll
        for (int k = 0; k < 12; ++k) { a1[k] = 0.f; a2[k] = 0.f; }
        float vr[36], wr[24], cr[24];
        const float* vp = &vl[(r + dy) * AST + xw];
#pragma unroll
        for (int c = 0; c < 9; ++c)
            *(float4*)&vr[4 * c] = *(const float4*)&vp[4 * c];
#pragma unroll
        for (int c = 0; c < 6; ++c) {
            *(float4*)&wr[4 * c] = *(const float4*)&wtl[dy * WPAD + 4 * c];
            *(float4*)&cr[4 * c] = *(const float4*)&wcl[dy * WPAD + 4 * c];
        }
#pragma unroll
        for (int dx = 0; dx < WIN; ++dx)
#pragma unroll
            for (int k = 0; k < 12; ++k) {
                a1[k] = fmaf(wr[dx], vr[k + 2 + dx], a1[k]);
                a2[k] = fmaf(cr[dx], vr[k + 2 + dx], a2[k]);
            }
#pragma unroll
        for (int c = 0; c < 3; ++c) {
            *(float4*)&p1[tid * 12 + 4 * c] = *(float4*)&a1[4 * c];
            *(float4*)&p2[tid * 12 + 4 * c] = *(float4*)&a2[4 * c];
        }
    }
    __syncthreads();

    float val = 0.f;
    if (tid < NOUT) {
        float s1 = 0.f, s2 = 0.f;
#pragma unroll
        for (int d = 0; d < WIN; ++d) {
            s1 += p1[d * 144 + tid];
            s2 += p2[d * 144 + tid];
        }
        const int o = b * N + (y0 + tid / 48) * 48 + (tid % 48);
        val = (target[o] + 1e-8f) / s1 * s2;
    }
    val = wave_sum(val);
    if (lane == 0) sred[w] = val;
    __syncthreads();
    if (tid == 0)
        atomicAdd(out, (sred[0] + sred[1] + sred[2] + sred[3]) * (1.f / 16.f));
}

}  // namespace

extern "C" void kernel_launch(void* const* d_in, const int* in_sizes, int n_in,
                              void* d_out, int out_size, void* d_ws, size_t ws_size,
                              hipStream_t stream) {
    const float* logits = (const float*)d_in[0];   // (B, 48, 48)
    const float* target = (const float*)d_in[1];   // (B, 48, 48)
    const float* C      = (const float*)d_in[2];   // (1, N, N)
    float* out = (float*)d_out;
    float* ws  = (float*)d_ws;

    float* smstat = ws;            // [32]
    float* A0     = ws + 32;       // [B][N]
    float* A1     = A0 + NB;       // [B][N]

    sk_a1<<<256, 256, 0, stream>>>(logits, C, smstat, A0, out);

    // 9 fused (b_t, a_{t+1}) dispatches, ping-pong; a10 lands in A1
    float* bufs[2] = {A0, A1};
    for (int t = 0; t < 9; ++t) {
        sk_fused<<<256, 512, 0, stream>>>(logits, target, C, smstat,
                                          bufs[t & 1], bufs[(t & 1) ^ 1]);
    }

    sk_cost<<<256, 256, 0, stream>>>(target, C, A1, out);
}

// Round 19
// 84.904 us; speedup vs baseline: 1.4566x; 1.1270x over previous
//
#include <hip/hip_runtime.h>

// Sinkhorn image loss — conv form (R=10), 10 dispatches, folded pair fusion.
//   K = exp(-C/eps) = exp(-1.5045*d_pix): radial 21x21 stencil (R=10 tail
//   ~3e-6 rel; absmax 0.0 verified rounds 13-18). Weights from C row 1176.
//   a1 = p/rowsum pointwise (rowsum = conv-of-ones = RECTANGLE SUM of the
//   21x21 weight table -> 2D prefix lookup, no conv needed, no a1 dispatch);
//   first fused kernel synthesizes the a1 apron + computes smstat in-block;
//   9 fused pairs total: first=(a1,b1,a2-pointwise+conv+conv), 8 regular;
//   cost (+b10) unchanged.
//
// vs round-16 champion (83.8us): dy-fold task bodies (w(dy)=w(-dy) bitwise,
// r17/r18-proven exact) with round-16's EXACT partial layout (scalar
// stride-25 stores — r18's f4 stride-26 stores were 8-way bank-conflicted,
// the suspected regression). No prefetch. 10 nodes instead of 11.

namespace {

constexpr int N    = 2304;   // 48*48
constexpr int B    = 16;
constexpr int NB   = N * B;
constexpr int R    = 10;
constexpr int WIN  = 21;
constexpr int WPAD = 24;
constexpr int APX  = 12;     // aligned x-apron; taps at word offset +2
constexpr int AST  = 76;     // LDS row stride (words)
constexpr int NOUT = 144;
constexpr int NTH  = WIN * 12;  // 252 (cost kernel)
constexpr int AVR1 = 23;     // apron rows, single conv (3+2R)
constexpr int AVR2 = 43;     // apron rows, fused (3+4R)
constexpr int BVR  = 23;     // b-tile rows
constexpr int PST  = 25;     // partial slot stride (odd -> conflict-free)
constexpr int P1L  = 46 * PST;   // 1150 words per conv1 fold level
constexpr int P2L  = 6 * PST;    // 150 words per conv2 fold level

__device__ __forceinline__ float wave_sum(float v) {
#pragma unroll
    for (int off = 32; off >= 1; off >>= 1) v += __shfl_xor(v, off);
    return v;
}

template <bool WC, int NT>
__device__ __forceinline__ void stage_wt(float* wtl, float* wcl,
                                         const float* __restrict__ C) {
    for (int i = threadIdx.x; i < WIN * WPAD; i += NT) {
        const int dy = i / WPAD, dx = i - dy * WPAD;
        float wv = 0.f, wc = 0.f;
        if (dx < WIN) {
            const float c = C[1176 * N + (14 + dy) * 48 + (14 + dx)];
            wv = __expf(c * -100.f);
            wc = wv * c;
        }
        wtl[i] = wv;
        if (WC) wcl[i] = wc;
    }
}

template <bool ONES, int NT>
__device__ __forceinline__ void stage_ap(float* vl, const float* img,
                                         int b, int ytop, int nrows) {
    for (int i = threadIdx.x; i < nrows * 18; i += NT) {
        const int rr = i / 18, c4 = i - rr * 18;
        const int y = ytop + rr, x0 = c4 * 4 - APX;
        float4 v = make_float4(0.f, 0.f, 0.f, 0.f);
        if ((unsigned)y < 48u && (unsigned)x0 < 48u)
            v = ONES ? make_float4(1.f, 1.f, 1.f, 1.f)
                     : *(const float4*)(img + b * N + y * 48 + x0);
        *(float4*)&vl[rr * AST + c4 * 4] = v;
    }
}

// ---- conv primitives (r16/r17/r18-proven): acc[k] += w[dx]*row[k+2+dx] ----
__device__ __forceinline__ void conv_c12(const float* vp, const float* wp,
                                         float* acc) {
    float vr[36], wr[24];
#pragma unroll
    for (int c = 0; c < 9; ++c) *(float4*)&vr[4 * c] = *(const float4*)&vp[4 * c];
#pragma unroll
    for (int c = 0; c < 6; ++c) *(float4*)&wr[4 * c] = *(const float4*)&wp[4 * c];
#pragma unroll
    for (int dx = 0; dx < WIN; ++dx)
#pragma unroll
        for (int k = 0; k < 12; ++k)
            acc[k] = fmaf(wr[dx], vr[k + 2 + dx], acc[k]);
}
__device__ __forceinline__ void conv_p12(const float* lo, const float* hi,
                                         const float* wp, float* acc) {
    float vr[36], wr[24];
#pragma unroll
    for (int c = 0; c < 9; ++c) {
        const float4 a = *(const float4*)&lo[4 * c];
        const float4 b = *(const float4*)&hi[4 * c];
        vr[4 * c]     = a.x + b.x;
        vr[4 * c + 1] = a.y + b.y;
        vr[4 * c + 2] = a.z + b.z;
        vr[4 * c + 3] = a.w + b.w;
    }
#pragma unroll
    for (int c = 0; c < 6; ++c) *(float4*)&wr[4 * c] = *(const float4*)&wp[4 * c];
#pragma unroll
    for (int dx = 0; dx < WIN; ++dx)
#pragma unroll
        for (int k = 0; k < 12; ++k)
            acc[k] = fmaf(wr[dx], vr[k + 2 + dx], acc[k]);
}
__device__ __forceinline__ void conv_c24(const float* vp, const float* wp,
                                         float* acc) {
    float vr[48], wr[24];
#pragma unroll
    for (int c = 0; c < 12; ++c) *(float4*)&vr[4 * c] = *(const float4*)&vp[4 * c];
#pragma unroll
    for (int c = 0; c < 6; ++c) *(float4*)&wr[4 * c] = *(const float4*)&wp[4 * c];
#pragma unroll
    for (int dx = 0; dx < WIN; ++dx)
#pragma unroll
        for (int k = 0; k < 24; ++k)
            acc[k] = fmaf(wr[dx], vr[k + 2 + dx], acc[k]);
}
__device__ __forceinline__ void conv_p24(const float* lo, const float* hi,
                                         const float* wp, float* acc) {
    float vr[48], wr[24];
#pragma unroll
    for (int c = 0; c < 12; ++c) {
        const float4 a = *(const float4*)&lo[4 * c];
        const float4 b = *(const float4*)&hi[4 * c];
        vr[4 * c]     = a.x + b.x;
        vr[4 * c + 1] = a.y + b.y;
        vr[4 * c + 2] = a.z + b.z;
        vr[4 * c + 3] = a.w + b.w;
    }
#pragma unroll
    for (int c = 0; c < 6; ++c) *(float4*)&wr[4 * c] = *(const float4*)&wp[4 * c];
#pragma unroll
    for (int dx = 0; dx < WIN; ++dx)
#pragma unroll
        for (int k = 0; k < 24; ++k)
            acc[k] = fmaf(wr[dx], vr[k + 2 + dx], acc[k]);
}

// ------------------------------------------------------------- fused ------
// FIRST: compute softmax stats in-block, build a1 apron pointwise
// (a1 = p / rectsum(weights)), write smstat (+zero out). Else stage from Ain.
// Then (folded) conv1 -> b-tile -> conv2 -> a-update. r16 partial layout.
template <bool FIRST>
__global__ __launch_bounds__(512) void sk_fused(const float* __restrict__ logits,
                                                const float* __restrict__ target,
                                                const float* __restrict__ C,
                                                float* __restrict__ smstat,
                                                const float* __restrict__ Ain,
                                                float* __restrict__ Aout,
                                                float* __restrict__ out) {
    __shared__ float vl[AVR2 * AST];    // 13072 B
    __shared__ float bt[BVR * AST];     //  6992 B
    __shared__ float part[11 * P1L];    // 50600 B (pfx scratch reuses this)
    __shared__ float wtl[WIN * WPAD];   //  2016 B
    __shared__ float sred[16];

    const int bid = blockIdx.x;
    const int b   = bid & 15;
    const int y0  = (bid >> 4) * 3;
    const int tid = threadIdx.x;

    stage_wt<false, 512>(wtl, nullptr, C);

    float sm_m, sm_inv;
    if constexpr (FIRST) {
        // ---- softmax stats for batch b (in-block, redundant) --------------
        const int w = tid >> 6, lane = tid & 63;
        float xs[5];
        float m = -3.0e38f;
#pragma unroll
        for (int k = 0; k < 5; ++k) {
            const int idx = tid + k * 512;
            xs[k] = (idx < N) ? logits[b * N + idx] : -3.0e38f;
            m = fmaxf(m, xs[k]);
        }
#pragma unroll
        for (int off = 32; off >= 1; off >>= 1) m = fmaxf(m, __shfl_xor(m, off));
        if (lane == 0) sred[w] = m;
        __syncthreads();
        m = sred[0];
#pragma unroll
        for (int i = 1; i < 8; ++i) m = fmaxf(m, sred[i]);
        float sum = 0.f;
#pragma unroll
        for (int k = 0; k < 5; ++k)
            if (tid + k * 512 < N) sum += __expf(xs[k] - m);
#pragma unroll
        for (int off = 32; off >= 1; off >>= 1) sum += __shfl_xor(sum, off);
        __syncthreads();
        if (lane == 0) sred[8 + w] = sum;
        __syncthreads();
        sum = 0.f;
#pragma unroll
        for (int i = 0; i < 8; ++i) sum += sred[8 + i];
        sm_m = m;
        sm_inv = 1.f / sum;
        if ((bid >> 4) == 0 && tid == 0) {
            smstat[2 * b]     = sm_m;
            smstat[2 * b + 1] = sm_inv;
            if (b == 0) out[0] = 0.f;
        }
        __syncthreads();   // wtl ready for prefix

        // ---- 2D inclusive prefix of weight table into part scratch --------
        float* pfx = part;   // 441 words, consumed before conv1 writes part
        if (tid < WIN) {
            float run = 0.f;
            for (int j = 0; j < WIN; ++j) {
                run += wtl[tid * WPAD + j];
                pfx[tid * WIN + j] = run;
            }
        }
        __syncthreads();
        if (tid < WIN) {
            float run = 0.f;
            for (int d = 0; d < WIN; ++d) {
                run += pfx[d * WIN + tid];
                pfx[d * WIN + tid] = run;
            }
        }
        __syncthreads();

        // ---- a1 apron: vl = p / rectsum, zero-padded ----------------------
        for (int i = tid; i < AVR2 * 72; i += 512) {
            const int rr = i / 72, cc = i - rr * 72;
            const int y = y0 - 2 * R + rr, x = cc - APX;
            float v = 0.f;
            if ((unsigned)y < 48u && (unsigned)x < 48u) {
                const int ulo = max(0, 10 - y), uhi = min(20, 57 - y);
                const int vlo = max(0, 10 - x), vhi = min(20, 57 - x);
                float rs = pfx[uhi * WIN + vhi];
                if (ulo) rs -= pfx[(ulo - 1) * WIN + vhi];
                if (vlo) rs -= pfx[uhi * WIN + (vlo - 1)];
                if (ulo && vlo) rs += pfx[(ulo - 1) * WIN + (vlo - 1)];
                v = __expf(logits[b * N + y * 48 + x] - sm_m) * sm_inv / rs;
            }
            vl[rr * AST + cc] = v;
        }
    } else {
        stage_ap<false, 512>(vl, Ain, b, y0 - 2 * R, AVR2);
        sm_m   = smstat[2 * b];
        sm_inv = smstat[2 * b + 1];
    }
    for (int i = tid; i < BVR * AST; i += 512) bt[i] = 0.f;
    __syncthreads();

    // ---- conv1 (folded): 506 tasks (u<11, rb<23, xg<2), r16 store layout --
    if (tid < 506) {
        const int u = tid / 46, slot = tid - u * 46;
        const int rb = slot >> 1, xw = (slot & 1) * 24;
        float acc[24];
#pragma unroll
        for (int k = 0; k < 24; ++k) acc[k] = 0.f;
        if (u == 0) conv_c24(&vl[(rb + 10) * AST + xw], &wtl[10 * WPAD], acc);
        else        conv_p24(&vl[(rb + 10 - u) * AST + xw],
                             &vl[(rb + 10 + u) * AST + xw],
                             &wtl[(10 + u) * WPAD], acc);
        float* pp = &part[u * P1L + slot * PST];
#pragma unroll
        for (int k = 0; k < 24; ++k) pp[k] = acc[k];
    }
    __syncthreads();

    // ---- reduce1 -> b-tile (r16 verbatim) ---------------------------------
    for (int o = tid; o < BVR * 48; o += 512) {
        const int rb = o / 48, x = o - rb * 48;
        const int slot = rb * 2 + (x >= 24 ? 1 : 0);
        const int k = x >= 24 ? x - 24 : x;
        float s = 0.f;
#pragma unroll
        for (int l = 0; l < 11; ++l) s += part[l * P1L + slot * PST + k];
        const int ybg = y0 - R + rb;
        if ((unsigned)ybg < 48u)
            bt[rb * AST + APX + x] = (target[b * N + ybg * 48 + x] + 1e-8f) / s;
    }
    __syncthreads();

    // ---- conv2 (folded): 66 tasks (u<11, ra<3, xg<2) ----------------------
    if (tid < 66) {
        const int u = tid / 6, slot = tid - u * 6;
        const int ra = slot >> 1, xw = (slot & 1) * 24;
        float acc[24];
#pragma unroll
        for (int k = 0; k < 24; ++k) acc[k] = 0.f;
        if (u == 0) conv_c24(&bt[(ra + 10) * AST + xw], &wtl[10 * WPAD], acc);
        else        conv_p24(&bt[(ra + 10 - u) * AST + xw],
                             &bt[(ra + 10 + u) * AST + xw],
                             &wtl[(10 + u) * WPAD], acc);
        float* pp = &part[u * P2L + slot * PST];
#pragma unroll
        for (int k = 0; k < 24; ++k) pp[k] = acc[k];
    }
    __syncthreads();

    // ---- reduce2 -> global (r16 verbatim) ---------------------------------
    if (tid < NOUT) {
        const int ra = tid / 48, x = tid - ra * 48;
        const int slot = ra * 2 + (x >= 24 ? 1 : 0);
        const int k = x >= 24 ? x - 24 : x;
        float s = 0.f;
#pragma unroll
        for (int l = 0; l < 11; ++l) s += part[l * P2L + slot * PST + k];
        const int g = b * N + (y0 + ra) * 48 + x;
        Aout[g] = __expf(logits[g] - sm_m) * sm_inv / s;
    }
}

// ------------------------------------------------------------- cost -------
// (verbatim round-13/16-proven) s1 = K a10, s2 = (K.C) a10; q/s1*s2; atomic.
__global__ __launch_bounds__(256) void sk_cost(const float* __restrict__ target,
                                               const float* __restrict__ C,
                                               const float* __restrict__ Ain,
                                               float* __restrict__ out) {
    __shared__ float vl[AVR1 * AST];
    __shared__ float wtl[WIN * WPAD], wcl[WIN * WPAD];
    __shared__ float p1[NTH * 12], p2[NTH * 12];
    __shared__ float sred[4];

    const int bid = blockIdx.x;
    const int b   = bid & 15;
    const int y0  = (bid >> 4) * 3;
    const int tid = threadIdx.x, w = tid >> 6, lane = tid & 63;

    stage_wt<true, 256>(wtl, wcl, C);
    stage_ap<false, 256>(vl, Ain, b, y0 - R, AVR1);
    __syncthreads();

    if (tid < NTH) {
        const int dy = tid / 12, strip = tid - dy * 12;
        const int r = strip >> 2, xw = (strip & 3) * 12;
        float a1[12], a2[12];
#pragma unroll
        for (int k = 0; k < 12; ++k) { a1[k] = 0.f; a2[k] = 0.f; }
        float vr[36], wr[24], cr[24];
        const float* vp = &vl[(r + dy) * AST + xw];
#pragma unroll
        for (int c = 0; c < 9; ++c)
            *(float4*)&vr[4 * c] = *(const float4*)&vp[4 * c];
#pragma unroll
        for (int c = 0; c < 6; ++c) {
            *(float4*)&wr[4 * c] = *(const float4*)&wtl[dy * WPAD + 4 * c];
            *(float4*)&cr[4 * c] = *(const float4*)&wcl[dy * WPAD + 4 * c];
        }
#pragma unroll
        for (int dx = 0; dx < WIN; ++dx)
#pragma unroll
            for (int k = 0; k < 12; ++k) {
                a1[k] = fmaf(wr[dx], vr[k + 2 + dx], a1[k]);
                a2[k] = fmaf(cr[dx], vr[k + 2 + dx], a2[k]);
            }
#pragma unroll
        for (int c = 0; c < 3; ++c) {
            *(float4*)&p1[tid * 12 + 4 * c] = *(float4*)&a1[4 * c];
            *(float4*)&p2[tid * 12 + 4 * c] = *(float4*)&a2[4 * c];
        }
    }
    __syncthreads();

    float val = 0.f;
    if (tid < NOUT) {
        float s1 = 0.f, s2 = 0.f;
#pragma unroll
        for (int d = 0; d < WIN; ++d) {
            s1 += p1[d * 144 + tid];
            s2 += p2[d * 144 + tid];
        }
        const int o = b * N + (y0 + tid / 48) * 48 + (tid % 48);
        val = (target[o] + 1e-8f) / s1 * s2;
    }
    val = wave_sum(val);
    if (lane == 0) sred[w] = val;
    __syncthreads();
    if (tid == 0)
        atomicAdd(out, (sred[0] + sred[1] + sred[2] + sred[3]) * (1.f / 16.f));
}

}  // namespace

extern "C" void kernel_launch(void* const* d_in, const int* in_sizes, int n_in,
                              void* d_out, int out_size, void* d_ws, size_t ws_size,
                              hipStream_t stream) {
    const float* logits = (const float*)d_in[0];   // (B, 48, 48)
    const float* target = (const float*)d_in[1];   // (B, 48, 48)
    const float* C      = (const float*)d_in[2];   // (1, N, N)
    float* out = (float*)d_out;
    float* ws  = (float*)d_ws;

    float* smstat = ws;            // [32]
    float* A0     = ws + 32;       // [B][N]
    float* A1     = A0 + NB;       // [B][N]

    // first fused: a1 (pointwise) + b1 + a2 -> A0
    sk_fused<true><<<256, 512, 0, stream>>>(logits, target, C, smstat,
                                            A1, A0, out);

    // 8 regular fused: (b2,a3)..(b9,a10); ping-pong; a10 lands in A0
    float* bufs[2] = {A0, A1};
    for (int t = 0; t < 8; ++t) {
        sk_fused<false><<<256, 512, 0, stream>>>(logits, target, C, smstat,
                                                 bufs[t & 1], bufs[(t & 1) ^ 1],
                                                 out);
    }

    sk_cost<<<256, 256, 0, stream>>>(target, C, A0, out);
}